// Round 3
// baseline (2724.807 us; speedup 1.0000x reference)
//
#include <hip/hip_runtime.h>
#include <math.h>
#include <stdint.h>
#include <stddef.h>

// Problem dims (hard-coded per reference)
#define B_ 512
#define H_ 512
#define E_ 512
#define V_ 2048
#define IN_ 1024
#define LSTEPS 32
#define LP1 33

// JAX threefry mode: 1 = partitionable (JAX >= 0.4.36 default), 0 = original
#define TF_PARTITIONABLE 1

// split-K factor for all GEMMs
#define SPLITK 4
#define PSTRIDE_GATES (B_ * 2048)      // 1048576 floats per partial (gates/logits)

__device__ __forceinline__ void tf2x32(uint32_t k0, uint32_t k1,
                                       uint32_t x0, uint32_t x1,
                                       uint32_t& o0, uint32_t& o1) {
  uint32_t ks2 = k0 ^ k1 ^ 0x1BD11BDAu;
  x0 += k0; x1 += k1;
#define TFR(R) { x0 += x1; x1 = (x1 << (R)) | (x1 >> (32 - (R))); x1 ^= x0; }
  TFR(13) TFR(15) TFR(26) TFR(6)
  x0 += k1; x1 += ks2 + 1u;
  TFR(17) TFR(29) TFR(16) TFR(24)
  x0 += ks2; x1 += k0 + 2u;
  TFR(13) TFR(15) TFR(26) TFR(6)
  x0 += k0; x1 += k1 + 3u;
  TFR(17) TFR(29) TFR(16) TFR(24)
  x0 += k1; x1 += ks2 + 4u;
  TFR(13) TFR(15) TFR(26) TFR(6)
  x0 += ks2; x1 += k0 + 5u;
#undef TFR
  o0 = x0; o1 = x1;
}

__global__ void init_keys_kernel(uint32_t* __restrict__ sk) {
  uint32_t k0 = 0u, k1 = 1u;
  for (int t = 0; t < LSTEPS; t++) {
    uint32_t a0, a1, b0, b1;
#if TF_PARTITIONABLE
    tf2x32(k0, k1, 0u, 0u, a0, a1);
    tf2x32(k0, k1, 0u, 1u, b0, b1);
    sk[2 * t] = b0; sk[2 * t + 1] = b1;
    k0 = a0; k1 = a1;
#else
    tf2x32(k0, k1, 0u, 2u, a0, a1);
    tf2x32(k0, k1, 1u, 3u, b0, b1);
    sk[2 * t] = a1; sk[2 * t + 1] = b1;
    k0 = a0; k1 = b0;
#endif
  }
}

__global__ __launch_bounds__(256) void init_state_kernel(
    const float* __restrict__ sos, float* __restrict__ c, float* __restrict__ e) {
  int idx = blockIdx.x * 256 + threadIdx.x;
  if (idx < B_ * H_) {
    c[idx] = 0.0f;
    e[idx] = sos[idx & (E_ - 1)];
  }
}

__global__ __launch_bounds__(256) void eos_fill_kernel(
    float* __restrict__ o_seq, float* __restrict__ o_probs,
    float* __restrict__ o_logp, float* __restrict__ o_ent) {
  int b = blockIdx.x, tid = threadIdx.x;
  float* pr = o_probs + ((size_t)b * LP1 + LSTEPS) * V_;
  for (int v = tid; v < V_; v += 256) pr[v] = 1.0f;
  if (tid == 0) {
    o_seq[b * LP1 + LSTEPS] = 0.0f;
    o_logp[b * LP1 + LSTEPS] = 0.0f;
    o_ent[b * LP1 + LSTEPS] = 0.0f;
  }
}

// ---- async global->LDS staging helper (16B per lane, wave-uniform LDS base)
typedef __attribute__((address_space(1))) const void GASV;
typedef __attribute__((address_space(3))) void LASV;
__device__ __forceinline__ void gld16(const void* g, void* l) {
  __builtin_amdgcn_global_load_lds((GASV*)g, (LASV*)l, 16, 0, 0);
}

// Split-K fp32 GEMM: P[z][128-row tile, 128-col tile] = A[:, kz..kz+KPB) @ B[kz.., :]
// 512 threads (8 waves -> 2 waves/SIMD for latency hiding), 8x4 micro-tile,
// double-buffered LDS, staging via global_load_lds width-16 (1 A + 1 B per thread/chunk).
// A source: rows m, cols k. k < kHalf -> A0 (stride strideA), else A1 (k-kHalf).
// grid = (M/128, N/128, SPLITK). Blocks never straddle kHalf.
__global__ __launch_bounds__(512) void gemm_splitk_kernel(
    const float* __restrict__ A0, const float* __restrict__ A1, int strideA,
    const float* __restrict__ B0, const float* __restrict__ B1,
    int N, int kHalf, int KPB, float* __restrict__ P, int pstride) {
  __shared__ float lds[2][4096];   // per buf: As[128][16] (2048 fl) + Bs[16][128] (2048 fl)
  int tid = threadIdx.x;
  int m0 = blockIdx.x * 128, n0 = blockIdx.y * 128;
  int k0 = blockIdx.z * KPB;
  bool hi = (k0 >= kHalf);
  const float* Ap = hi ? A1 : A0;
  const float* Bp = hi ? B1 : B0;
  int kb = hi ? (k0 - kHalf) : k0;

  int w = tid >> 6;                 // wave id (LDS stage base, wave-uniform)
  int arow = tid >> 2;              // 0..127 : A row
  int akc = (tid & 3) * 4;          // k sub-offset
  int brow = tid >> 5;              // 0..15 : B k-row
  int bcol = (tid & 31) * 4;        // 0..124 : B col
  int ty = tid >> 5;                // 0..15 : row group
  int tx = tid & 31;                // 0..31 : col group (4 cols)

  float acc[8][4] = {};
  int nch = KPB >> 4;               // chunks of BK=16

#define STAGE(CH, TB) {                                                         \
    int kc = kb + ((CH) << 4);                                                  \
    gld16(Ap + (size_t)(m0 + arow) * strideA + kc + akc,                        \
          (char*)&lds[TB][0] + w * 1024);                                       \
    gld16(Bp + (size_t)(kc + brow) * N + n0 + bcol,                             \
          (char*)&lds[TB][2048] + w * 1024);                                    \
  }

  STAGE(0, 0)
  for (int ch = 0; ch < nch; ch++) {
    __syncthreads();                 // drains vmcnt -> buf[ch&1] ready
    if (ch + 1 < nch) STAGE(ch + 1, (ch + 1) & 1)
    const float* As = &lds[ch & 1][0];
    const float* Bs = &lds[ch & 1][2048];
#pragma unroll
    for (int kg = 0; kg < 4; kg++) {
      float4 a[8], bq[4];
#pragma unroll
      for (int i = 0; i < 4; i++) {
        a[i]     = *(const float4*)&As[(ty * 4 + i) * 16 + kg * 4];
        a[i + 4] = *(const float4*)&As[(64 + ty * 4 + i) * 16 + kg * 4];
      }
#pragma unroll
      for (int kk = 0; kk < 4; kk++) bq[kk] = *(const float4*)&Bs[(kg * 4 + kk) * 128 + tx * 4];
#pragma unroll
      for (int kk = 0; kk < 4; kk++) {
#pragma unroll
        for (int i = 0; i < 8; i++) {
          float av = ((const float*)&a[i])[kk];
          acc[i][0] += av * ((const float*)&bq[kk])[0];
          acc[i][1] += av * ((const float*)&bq[kk])[1];
          acc[i][2] += av * ((const float*)&bq[kk])[2];
          acc[i][3] += av * ((const float*)&bq[kk])[3];
        }
      }
    }
  }
#undef STAGE

  float* Pb = P + (size_t)blockIdx.z * pstride;
#pragma unroll
  for (int i = 0; i < 8; i++) {
    int row = m0 + ((i < 4) ? (ty * 4 + i) : (64 + ty * 4 + i - 4));
    float4 o;
    o.x = acc[i][0]; o.y = acc[i][1]; o.z = acc[i][2]; o.w = acc[i][3];
    *(float4*)&Pb[(size_t)row * N + n0 + tx * 4] = o;
  }
}

__device__ __forceinline__ float sigm(float x) { return 1.0f / (1.0f + expf(-x)); }

// Sum SPLITK gate partials + biases, apply LSTM cell. One float4 of H per thread.
__global__ __launch_bounds__(256) void cell_reduce_kernel(
    const float* __restrict__ P,
    const float* __restrict__ b_ih, const float* __restrict__ b_hh,
    float* __restrict__ c, float* __restrict__ h) {
  int idx = blockIdx.x * 256 + threadIdx.x;   // float4 index in [B, H] space
  int b = idx >> 7;
  int h4 = (idx & 127) * 4;
  float4 g4[4];
#pragma unroll
  for (int g = 0; g < 4; g++) {
    size_t off = (size_t)b * 2048 + g * 512 + h4;
    float4 s = *(const float4*)&P[off];
#pragma unroll
    for (int sgl = 1; sgl < SPLITK; sgl++) {
      float4 p = *(const float4*)&P[(size_t)sgl * PSTRIDE_GATES + off];
      s.x += p.x; s.y += p.y; s.z += p.z; s.w += p.w;
    }
    float4 bi = *(const float4*)&b_ih[g * 512 + h4];
    float4 bh = *(const float4*)&b_hh[g * 512 + h4];
    s.x += bi.x + bh.x; s.y += bi.y + bh.y; s.z += bi.z + bh.z; s.w += bi.w + bh.w;
    g4[g] = s;
  }
  size_t ci = (size_t)b * 512 + h4;
  float4 cold = *(const float4*)&c[ci];
  float4 cn, hn;
  {
    const float* ig = (const float*)&g4[0];
    const float* fg = (const float*)&g4[1];
    const float* gg = (const float*)&g4[2];
    const float* og = (const float*)&g4[3];
    float* cc = (float*)&cn; float* hh = (float*)&hn;
    const float* co = (const float*)&cold;
#pragma unroll
    for (int k = 0; k < 4; k++) {
      float cv = sigm(fg[k]) * co[k] + sigm(ig[k]) * tanhf(gg[k]);
      cc[k] = cv;
      hh[k] = sigm(og[k]) * tanhf(cv);
    }
  }
  *(float4*)&c[ci] = cn;
  *(float4*)&h[ci] = hn;
}

// Sum SPLITK partials + bias -> out (used once for h0). N = row width.
__global__ __launch_bounds__(256) void reduce_bias_kernel(
    const float* __restrict__ P, int pstride, const float* __restrict__ bias,
    float* __restrict__ out, int N, int total4) {
  int idx = blockIdx.x * 256 + threadIdx.x;
  if (idx >= total4) return;
  size_t off = (size_t)idx * 4;
  float4 s = *(const float4*)&P[off];
#pragma unroll
  for (int sgl = 1; sgl < SPLITK; sgl++) {
    float4 p = *(const float4*)&P[(size_t)sgl * pstride + off];
    s.x += p.x; s.y += p.y; s.z += p.z; s.w += p.w;
  }
  int col = (int)(off % N);
  float4 bv = *(const float4*)&bias[col];
  s.x += bv.x; s.y += bv.y; s.z += bv.z; s.w += bv.w;
  *(float4*)&out[off] = s;
}

// Per-row: reduce logits partials (+out_b), log_softmax, entropy, probs write,
// threefry gumbel argmax sample, logp gather, embedding gather.
// One block of 512 threads per row; 4 logits per thread.
__global__ __launch_bounds__(512) void sample_step_kernel(
    const float* __restrict__ P, const float* __restrict__ out_b,
    const uint32_t* __restrict__ skv,
    const float* __restrict__ embedding, float* __restrict__ e,
    float* __restrict__ o_seq, float* __restrict__ o_probs,
    float* __restrict__ o_logp, float* __restrict__ o_ent, int t) {
  __shared__ float zs[V_];
  __shared__ float rmax[8], rsum[8], rps[8], rav[8];
  __shared__ int rai[8];
  int tid = threadIdx.x, b = blockIdx.x;
  int wid = tid >> 6;
  const float* pr0 = P + (size_t)b * V_ + tid * 4;
  float4 za = *(const float4*)pr0;
#pragma unroll
  for (int s = 1; s < SPLITK; s++) {
    float4 pa = *(const float4*)(pr0 + (size_t)s * PSTRIDE_GATES);
    za.x += pa.x; za.y += pa.y; za.z += pa.z; za.w += pa.w;
  }
  {
    float4 oa = *(const float4*)(out_b + tid * 4);
    za.x += oa.x; za.y += oa.y; za.z += oa.z; za.w += oa.w;
  }
  float zv[4] = {za.x, za.y, za.z, za.w};
  *(float4*)&zs[tid * 4] = za;

  float m = fmaxf(fmaxf(zv[0], zv[1]), fmaxf(zv[2], zv[3]));
  for (int off = 32; off; off >>= 1) m = fmaxf(m, __shfl_xor(m, off));
  if ((tid & 63) == 0) rmax[wid] = m;
  __syncthreads();
#pragma unroll
  for (int w2 = 1; w2 < 8; w2++) m = fmaxf(m, rmax[w2]);
  m = fmaxf(m, rmax[0]);

  float sh[4];
  float ssum = 0.f;
#pragma unroll
  for (int i = 0; i < 4; i++) { sh[i] = zv[i] - m; ssum += expf(sh[i]); }
  for (int off = 32; off; off >>= 1) ssum += __shfl_xor(ssum, off);
  if ((tid & 63) == 0) rsum[wid] = ssum;
  __syncthreads();
  float S = 0.f;
#pragma unroll
  for (int w2 = 0; w2 < 8; w2++) S += rsum[w2];
  float ls = logf(S);

  uint32_t sk0 = skv[2 * t], sk1 = skv[2 * t + 1];
  float psum = 0.f;
  float best = -INFINITY;
  int bi = 0;
  float pv[4];
#pragma unroll
  for (int i = 0; i < 4; i++) {
    float s = sh[i] - ls;
    float p = expf(s);
    pv[i] = p;
    psum += p * s;
    int v = tid * 4 + i;
    uint32_t o0, o1, bits;
#if TF_PARTITIONABLE
    uint32_t j = (uint32_t)(b * V_ + v);
    tf2x32(sk0, sk1, 0u, j, o0, o1);
    bits = o0 ^ o1;
#else
    uint32_t j = (uint32_t)(b * V_ + v);
    const uint32_t n2 = (uint32_t)(B_ * V_ / 2);
    if (j < n2) { tf2x32(sk0, sk1, j, j + n2, o0, o1); bits = o0; }
    else       { tf2x32(sk0, sk1, j - n2, j, o0, o1); bits = o1; }
#endif
    float f = __uint_as_float((bits >> 9) | 0x3f800000u) - 1.0f;
    float u = fmaxf(f, 1.17549435e-38f);
    float g = -logf(-logf(u));
    float a = s + g;
    if (a > best) { best = a; bi = v; }
  }
  float* prw = o_probs + ((size_t)b * LP1 + t) * V_ + tid * 4;
  *(float4*)prw = make_float4(pv[0], pv[1], pv[2], pv[3]);

  for (int off = 32; off; off >>= 1) psum += __shfl_xor(psum, off);
  for (int off = 32; off; off >>= 1) {
    float ov = __shfl_xor(best, off);
    int oi = __shfl_xor(bi, off);
    if (ov > best || (ov == best && oi < bi)) { best = ov; bi = oi; }
  }
  if ((tid & 63) == 0) { rps[wid] = psum; rav[wid] = best; rai[wid] = bi; }
  __syncthreads();
  float ent = 0.f;
#pragma unroll
  for (int w2 = 0; w2 < 8; w2++) ent += rps[w2];
  ent = -ent;
  float bv2 = rav[0]; int sym = rai[0];
#pragma unroll
  for (int w2 = 1; w2 < 8; w2++) {
    if (rav[w2] > bv2 || (rav[w2] == bv2 && rai[w2] < sym)) { bv2 = rav[w2]; sym = rai[w2]; }
  }
  // gather next embedding (E_=512 floats = 128 float4)
  if (tid < 128) {
    ((float4*)(e + (size_t)b * E_))[tid] = ((const float4*)(embedding + (size_t)sym * E_))[tid];
  }
  if (tid == 0) {
    float s_sym = (zs[sym] - m) - ls;
    o_seq[b * LP1 + t] = (float)sym;
    o_logp[b * LP1 + t] = s_sym;
    o_ent[b * LP1 + t] = ent;
  }
}

extern "C" void kernel_launch(void* const* d_in, const int* in_sizes, int n_in,
                              void* d_out, int out_size, void* d_ws, size_t ws_size,
                              hipStream_t stream) {
  (void)in_sizes; (void)n_in; (void)out_size; (void)ws_size;
  const float* x     = (const float*)d_in[0];
  const float* agw   = (const float*)d_in[1];
  const float* agb   = (const float*)d_in[2];
  const float* sos   = (const float*)d_in[3];
  const float* emb   = (const float*)d_in[4];
  const float* w_ih  = (const float*)d_in[5];
  const float* w_hh  = (const float*)d_in[6];
  const float* b_ih  = (const float*)d_in[7];
  const float* b_hh  = (const float*)d_in[8];
  const float* out_w = (const float*)d_in[9];
  const float* out_b = (const float*)d_in[10];

  char* w = (char*)d_ws;
  uint32_t* sk = (uint32_t*)w;                                // 256 B used
  float* e  = (float*)(w + 1024);                             // 1 MB
  float* hA = (float*)(w + 1024 + 1 * 1048576);               // 1 MB
  float* hB = (float*)(w + 1024 + 2 * 1048576);               // 1 MB
  float* c  = (float*)(w + 1024 + 3 * 1048576);               // 1 MB
  float* P  = (float*)(w + 1024 + 4 * 1048576);               // 16 MB partials

  float* out = (float*)d_out;
  float* o_seq   = out;                                       // [512,33]
  float* o_probs = out + (size_t)B_ * LP1;                    // [512,33,2048]
  float* o_logp  = o_probs + (size_t)B_ * LP1 * V_;           // [512,33]
  float* o_ent   = o_logp + (size_t)B_ * LP1;                 // [512,33]

  const int BIG = 1 << 30;

  init_keys_kernel<<<1, 1, 0, stream>>>(sk);
  init_state_kernel<<<(B_ * H_ + 255) / 256, 256, 0, stream>>>(sos, c, e);
  eos_fill_kernel<<<B_, 256, 0, stream>>>(o_seq, o_probs, o_logp, o_ent);

  // h0 = x @ agent_w + agent_b   (M=512,N=512,K=1024; split-K 4, KPB=256)
  gemm_splitk_kernel<<<dim3(B_ / 128, H_ / 128, SPLITK), 512, 0, stream>>>(
      x, x, IN_, agw, agw, H_, BIG, IN_ / SPLITK, P, B_ * H_);
  reduce_bias_kernel<<<(B_ * H_ / 4 + 255) / 256, 256, 0, stream>>>(
      P, B_ * H_, agb, hA, H_, B_ * H_ / 4);

  for (int t = 0; t < LSTEPS; t++) {
    float* hin  = (t & 1) ? hB : hA;
    float* hout = (t & 1) ? hA : hB;
    // gates = [e|h] @ [w_ih; w_hh]  (K=1024, KPB=256, kHalf=512)
    gemm_splitk_kernel<<<dim3(B_ / 128, 2048 / 128, SPLITK), 512, 0, stream>>>(
        e, hin, E_, w_ih, w_hh, 4 * H_, E_, (E_ + H_) / SPLITK, P, PSTRIDE_GATES);
    cell_reduce_kernel<<<B_ * H_ / 4 / 256, 256, 0, stream>>>(P, b_ih, b_hh, c, hout);
    // logits partials = h @ out_w  (K=512, KPB=128)
    gemm_splitk_kernel<<<dim3(B_ / 128, V_ / 128, SPLITK), 512, 0, stream>>>(
        hout, hout, H_, out_w, out_w, V_, BIG, H_ / SPLITK, P, PSTRIDE_GATES);
    sample_step_kernel<<<B_, 512, 0, stream>>>(
        P, out_b, sk, emb, e, o_seq, o_probs, o_logp, o_ent, t);
  }
}